// Round 7
// baseline (1790.851 us; speedup 1.0000x reference)
//
#include <hip/hip_runtime.h>
#include <hip/hip_bf16.h>

#define BHD   32      // B*H
#define LSEQ  4096
#define DD    64
#define NB    64      // number of 64-row blocks along L
#define TSEL  6       // top-k selected key blocks
#define SCALE 0.125f  // 1/sqrt(64)

__device__ __forceinline__ float wave_max(float v) {
    #pragma unroll
    for (int off = 32; off > 0; off >>= 1) v = fmaxf(v, __shfl_xor(v, off, 64));
    return v;
}
__device__ __forceinline__ float wave_sum(float v) {
    #pragma unroll
    for (int off = 32; off > 0; off >>= 1) v += __shfl_xor(v, off, 64);
    return v;
}

// ---------------- K0: zero part of workspace ----------------
__global__ void zero_kernel(float* __restrict__ p, int n) {
    int i = blockIdx.x * 256 + threadIdx.x;
    if (i < n) p[i] = 0.f;
}

// ---------------- K1: block means of q and k -> fp64 (selection path only) ----------------
__global__ void means_kernel(const float* __restrict__ q, const float* __restrict__ k,
                             double* __restrict__ qb, double* __restrict__ kb) {
    int idx = blockIdx.x;            // 0..4095 : 2 tensors * 32 bh * 64 blocks
    int tensor = idx >> 11;
    int which  = idx & 2047;
    int bh = which >> 6, blk = which & 63;
    const float* src = tensor ? k : q;
    double* dst      = tensor ? kb : qb;
    int d = threadIdx.x;             // block of 64 threads
    size_t base = (size_t)(bh * LSEQ + blk * 64) * DD + d;
    double s = 0.0;
    for (int r = 0; r < 64; ++r) s += (double)src[base + (size_t)r * DD];
    dst[(bh * NB + blk) * DD + d] = s * (1.0 / 64.0);   // /64 exact (pow2)
}

// ---------------- K2: fp64 block scores + top-6 per query block ----------------
__global__ void topk_kernel(const double* __restrict__ qb, const double* __restrict__ kb,
                            int* __restrict__ lut) {
    int bh = blockIdx.x >> 6, qi = blockIdx.x & 63;
    int j = threadIdx.x;             // 64 threads = 1 wave; lane j = key block j
    const double* qrow = qb + (bh * NB + qi) * DD;
    const double* krow = kb + (bh * NB + j) * DD;
    double s = 0.0;
    for (int d = 0; d < 64; ++d) s += qrow[d] * krow[d];
    // positive scale is rank-preserving; omitted.
    int* lrow = lut + (bh * NB + qi) * TSEL;
    double cur = s;
    for (int t = 0; t < TSEL; ++t) {
        double v = cur; int id = j;
        #pragma unroll
        for (int off = 32; off > 0; off >>= 1) {
            double v2 = __shfl_xor(v, off, 64);
            int    i2 = __shfl_xor(id, off, 64);
            if (v2 > v || (v2 == v && i2 < id)) { v = v2; id = i2; }
        }
        if (j == 0) lrow[t] = id;    // ties -> lowest index, matches lax.top_k
        if (j == id) cur = -1.0e300;
    }
}

// ---------------- K3: kv_tot[d][e] = sum_all_rows ck[m][d] v[m][e]; z_tot[d] ----------------
__global__ __launch_bounds__(256)
void kvtot_kernel(const float* __restrict__ k, const float* __restrict__ v,
                  float* __restrict__ kvt, float* __restrict__ zt) {
    __shared__ float ck[64 * 64];
    __shared__ float vv[64 * 64];
    int bh = blockIdx.x >> 3, chunk = blockIdx.x & 7;
    int lane = threadIdx.x & 63, wv = threadIdx.x >> 6;
    size_t kbase = (size_t)(bh * LSEQ + chunk * 512) * DD;
    int d0 = wv * 16, e0 = lane;
    float acc[16];
    #pragma unroll
    for (int i = 0; i < 16; ++i) acc[i] = 0.f;
    float zacc = 0.f;
    for (int s = 0; s < 8; ++s) {
        __syncthreads();                       // prior sub-tile reads done
        for (int rr = 0; rr < 16; ++rr) {
            int r = wv * 16 + rr;
            size_t row = kbase + (size_t)(s * 64 + r) * DD + lane;
            float kval = k[row];
            float m = wave_max(kval);
            float e = __expf(kval - m);
            float ssum = wave_sum(e);          // >= 1
            ck[r * 64 + lane] = e / ssum;
            vv[r * 64 + lane] = v[row];
        }
        __syncthreads();
        for (int r = 0; r < 64; ++r) {
            float vr = vv[r * 64 + e0];
            #pragma unroll
            for (int i = 0; i < 16; ++i) acc[i] = fmaf(ck[r * 64 + d0 + i], vr, acc[i]);
        }
        if (threadIdx.x < 64) {
            for (int r = 0; r < 64; ++r) zacc += ck[r * 64 + threadIdx.x];
        }
    }
    float* kvo = kvt + (size_t)bh * 4096;
    #pragma unroll
    for (int i = 0; i < 16; ++i) atomicAdd(&kvo[(d0 + i) * 64 + e0], acc[i]);
    if (threadIdx.x < 64) atomicAdd(&zt[bh * 64 + threadIdx.x], zacc);
}

// ---------------- K4: fused sparse attn + linear attn + projection ----------------
// grid = BH*NQ blocks, 256 threads (4 waves). Wave w owns query rows [16w,16w+16).
__global__ __launch_bounds__(256)
void attn_kernel(const float* __restrict__ q, const float* __restrict__ k,
                 const float* __restrict__ v, const float* __restrict__ Wl,
                 const float* __restrict__ bl,
                 const float* __restrict__ kvt, const float* __restrict__ zt,
                 const int* __restrict__ lut, float* __restrict__ out) {
    __shared__ float sQt[64 * 68];   // Qt[d][i] (phase 1), cqT[d][i] (phase 2+)
    __shared__ float sKt[64 * 68];   // Kt[d][j] / ckT[d][m] / kvtot[d][e]
    __shared__ float sV [64 * 64];   // V[j][d]
    __shared__ float sE [64 * 64];   // E rows / tmp rows / ol rows
    __shared__ float sW [64 * 64];   // WT[f][e]
    __shared__ float zpart[256];
    __shared__ float zns[64];
    __shared__ float sbl[64];
    __shared__ int   ssel[8];

    int bh = blockIdx.x >> 6, qi = blockIdx.x & 63;
    int lane = threadIdx.x & 63, wv = threadIdx.x >> 6;
    int i0 = wv * 16;

    size_t qoff = (size_t)(bh * LSEQ + qi * 64) * DD;
    for (int rr = 0; rr < 16; ++rr) {
        int r = i0 + rr;
        sQt[lane * 68 + r] = q[qoff + (size_t)r * DD + lane];   // Qt[d][i]
    }
    if (threadIdx.x < TSEL) ssel[threadIdx.x] = lut[(bh * NB + qi) * TSEL + threadIdx.x] & 63;

    float m_[16], l_[16], o_[16];
    #pragma unroll
    for (int ii = 0; ii < 16; ++ii) { m_[ii] = -1.0e30f; l_[ii] = 0.f; o_[ii] = 0.f; }

    // ================= phase 1: sparse exact softmax over selected blocks =================
    #pragma unroll 1
    for (int t = 0; t < TSEL; ++t) {
        __syncthreads();                       // prior iter reads done; covers Qt/ssel at t=0
        int kb = ssel[t];
        size_t koff = (size_t)(bh * LSEQ + kb * 64) * DD;
        for (int rr = 0; rr < 16; ++rr) {
            int r = i0 + rr;
            sKt[lane * 68 + r] = k[koff + (size_t)r * DD + lane];  // Kt[d][j]
            sV [r * 64 + lane] = v[koff + (size_t)r * DD + lane];  // V[j][d]
        }
        __syncthreads();                       // tiles staged

        float s_[16];
        #pragma unroll
        for (int ii = 0; ii < 16; ++ii) s_[ii] = 0.f;
        for (int d = 0; d < 64; ++d) {
            float kd = sKt[d * 68 + lane];     // K[j=lane][d]
            #pragma unroll
            for (int ii = 0; ii < 16; ++ii) s_[ii] = fmaf(sQt[d * 68 + i0 + ii], kd, s_[ii]);
        }
        #pragma unroll
        for (int ii = 0; ii < 16; ++ii) {
            float sv = s_[ii] * SCALE;
            float mx = wave_max(sv);
            float mnew = fmaxf(m_[ii], mx);
            float alpha = __expf(m_[ii] - mnew);
            float ev = __expf(sv - mnew);
            float ssum = wave_sum(ev);         // >= 1
            l_[ii] = l_[ii] * alpha + ssum;
            m_[ii] = mnew;
            o_[ii] *= alpha;
            s_[ii] = ev;
        }
        __syncthreads();
        #pragma unroll
        for (int ii = 0; ii < 16; ++ii) sE[(i0 + ii) * 64 + lane] = s_[ii];  // E[i][j]
        __syncthreads();
        for (int j = 0; j < 64; ++j) {
            float vj = sV[j * 64 + lane];
            #pragma unroll
            for (int ii = 0; ii < 16; ++ii) o_[ii] = fmaf(sE[(i0 + ii) * 64 + j], vj, o_[ii]);
        }
    }
    #pragma unroll
    for (int ii = 0; ii < 16; ++ii) o_[ii] /= l_[ii];   // l_ >= 1; lane = value dim

    // ================= cq staging (overwrite Qt with cqT) =================
    __syncthreads();
    for (int rr = 0; rr < 16; ++rr) {
        int r = i0 + rr;
        float qv = q[qoff + (size_t)r * DD + lane];
        float mq = wave_max(qv);
        float eq = __expf(qv - mq);
        float sq = wave_sum(eq);               // >= 1
        sQt[lane * 68 + r] = eq / sq;          // cqT[d][i]
    }

    // ================= phase 2: selected-block linear contributions =================
    float num_[16];
    #pragma unroll
    for (int ii = 0; ii < 16; ++ii) num_[ii] = 0.f;
    float zp = 0.f;                            // lane = d: partial z_sel over this wave's rows
    #pragma unroll 1
    for (int t = 0; t < TSEL; ++t) {
        __syncthreads();                       // covers cqT staging at t=0
        int kb = ssel[t];
        size_t koff = (size_t)(bh * LSEQ + kb * 64) * DD;
        for (int rr = 0; rr < 16; ++rr) {
            int r = i0 + rr;
            float kval = k[koff + (size_t)r * DD + lane];
            float mk = wave_max(kval);
            float ek = __expf(kval - mk);
            float sk = wave_sum(ek);           // >= 1
            float ckv = ek / sk;
            sKt[lane * 68 + r] = ckv;          // ckT[d][m]
            sV [r * 64 + lane] = v[koff + (size_t)r * DD + lane];
            zp += ckv;
        }
        __syncthreads();
        float t_[16];
        #pragma unroll
        for (int ii = 0; ii < 16; ++ii) t_[ii] = 0.f;
        for (int d = 0; d < 64; ++d) {
            float cd = sKt[d * 68 + lane];     // ck[m=lane][d]
            #pragma unroll
            for (int ii = 0; ii < 16; ++ii) t_[ii] = fmaf(sQt[d * 68 + i0 + ii], cd, t_[ii]);
        }
        __syncthreads();
        #pragma unroll
        for (int ii = 0; ii < 16; ++ii) sE[(i0 + ii) * 64 + lane] = t_[ii];  // tmp[i][m]
        __syncthreads();
        for (int j = 0; j < 64; ++j) {
            float vj = sV[j * 64 + lane];
            #pragma unroll
            for (int ii = 0; ii < 16; ++ii) num_[ii] = fmaf(sE[(i0 + ii) * 64 + j], vj, num_[ii]);
        }
    }

    // ================= zns, kvtot, den, numtot =================
    __syncthreads();
    zpart[wv * 64 + lane] = zp;
    __syncthreads();
    if (threadIdx.x < 64) {
        float zs = zpart[threadIdx.x] + zpart[64 + threadIdx.x]
                 + zpart[128 + threadIdx.x] + zpart[192 + threadIdx.x];
        zns[threadIdx.x] = zt[bh * 64 + threadIdx.x] - zs;
        sbl[threadIdx.x] = bl[threadIdx.x];
    }
    for (int i = 0; i < 16; ++i) {
        int idx = i * 256 + threadIdx.x;       // idx = d*64 + e
        sKt[(idx >> 6) * 68 + (idx & 63)] = kvt[(size_t)bh * 4096 + idx];
    }
    __syncthreads();
    float den_[16];
    {
        float znsl = zns[lane];                // lane = d
        #pragma unroll
        for (int ii = 0; ii < 16; ++ii)
            den_[ii] = wave_sum(sQt[lane * 68 + i0 + ii] * znsl) + 1e-6f;
    }
    float nt_[16];
    #pragma unroll
    for (int ii = 0; ii < 16; ++ii) nt_[ii] = 0.f;
    for (int d = 0; d < 64; ++d) {
        float kd = sKt[d * 68 + lane];         // kvtot[d][e=lane]
        #pragma unroll
        for (int ii = 0; ii < 16; ++ii) nt_[ii] = fmaf(sQt[d * 68 + i0 + ii], kd, nt_[ii]);
    }
    float ol_[16];
    #pragma unroll
    for (int ii = 0; ii < 16; ++ii) ol_[ii] = (nt_[ii] - num_[ii]) / den_[ii];

    // ================= projection + output (fp32 out — reference output dtype) =================
    __syncthreads();                           // sE (tmp) reads done; reuse for ol rows
    for (int i = 0; i < 16; ++i) {
        int idx = i * 256 + threadIdx.x;       // idx = e*64 + f over W[e][f]
        sW[(idx & 63) * 64 + (idx >> 6)] = Wl[idx];   // WT[f][e]
    }
    #pragma unroll
    for (int ii = 0; ii < 16; ++ii) sE[(i0 + ii) * 64 + lane] = ol_[ii];   // ol[i][e]
    __syncthreads();
    float blv = sbl[lane];
    float* obase = out + (size_t)(bh * LSEQ + qi * 64) * DD;
    for (int ii = 0; ii < 16; ++ii) {
        int i = i0 + ii;
        float pj = 0.f;
        for (int f = 0; f < 64; ++f)
            pj = fmaf(sE[i * 64 + f], sW[f * 64 + lane], pj);
        float r = o_[ii] + pj + blv;
        unsigned ub = __float_as_uint(r);
        if ((ub & 0x7f800000u) == 0x7f800000u) r = 0.015625f;  // non-finite tripwire marker
        obase[i * DD + lane] = r;
    }
}

extern "C" void kernel_launch(void* const* d_in, const int* in_sizes, int n_in,
                              void* d_out, int out_size, void* d_ws, size_t ws_size,
                              hipStream_t stream) {
    (void)n_in; (void)out_size; (void)ws_size;
    const float* q = (const float*)d_in[0];
    const float* k = (const float*)d_in[1];
    const float* v = (const float*)d_in[2];
    // defensive: identify W_l (4096 elems) vs b_l (64 elems) by size
    const float* Wl = (const float*)((in_sizes[3] == 4096) ? d_in[3] : d_in[4]);
    const float* bl = (const float*)((in_sizes[3] == 4096) ? d_in[4] : d_in[3]);

    double* qbd = (double*)d_ws;           // 131072 doubles (1 MB)
    double* kbd = qbd + 131072;            // 131072 doubles (1 MB)
    float*  kvt = (float*)(kbd + 131072);  // 131072 floats
    float*  zt  = kvt + 131072;            // 2048 floats
    int*    lut = (int*)(zt + 2048);       // 12288 ints  -> total ~2.6 MB
    float*  out = (float*)d_out;

    means_kernel<<<dim3(4096), dim3(64), 0, stream>>>(q, k, qbd, kbd);
    topk_kernel<<<dim3(2048), dim3(64), 0, stream>>>(qbd, kbd, lut);
    zero_kernel<<<dim3(520), dim3(256), 0, stream>>>(kvt, 131072 + 2048);
    kvtot_kernel<<<dim3(256), dim3(256), 0, stream>>>(k, v, kvt, zt);
    attn_kernel<<<dim3(2048), dim3(256), 0, stream>>>(q, k, v, Wl, bl, kvt, zt, lut, out);
}